// Round 4
// baseline (3725.161 us; speedup 1.0000x reference)
//
#include <hip/hip_runtime.h>

typedef unsigned short bf16_t;
typedef uint4  __attribute__((may_alias)) uint4_a;
typedef uint2  __attribute__((may_alias)) uint2_a;
typedef float4 __attribute__((may_alias)) float4_a;
typedef short bf16x8 __attribute__((ext_vector_type(8)));
typedef bf16x8 __attribute__((may_alias)) bf16x8_a;
typedef float f32x4 __attribute__((ext_vector_type(4)));

#define MFMA16(a, b, c) __builtin_amdgcn_mfma_f32_16x16x32_bf16((a), (b), (c), 0, 0, 0)

constexpr int kS  = 256;
constexpr int kR  = 384;
constexpr int kCM = 256;
constexpr int kCZ = 128;
constexpr int kC  = 32;
constexpr int kH  = 8;
constexpr int kP  = kR * kR;        // 147456
constexpr int kM  = kS * kR;        // 98304

#define EPSF 1e-5f
#define SCALEF 0.17677669529663687f
// BiasL flat-index swizzle (involution, 16-elem granule)
#define BSWZ(i) ((i) ^ ((((i) >> 8) & 7) << 4))

__device__ __forceinline__ float bf2f(bf16_t u) {
  return __uint_as_float(((unsigned int)u) << 16);
}
__device__ __forceinline__ bf16_t f2bf(float f) {
  unsigned int u = __float_as_uint(f);
  u += 0x7fffu + ((u >> 16) & 1u);
  return (bf16_t)(u >> 16);
}

// ---------------- pair: stats + fp32->bf16 convert, fused, vectorized ----------------
__global__ __launch_bounds__(256) void k_pair_fused(const float* __restrict__ pair,
                                                    bf16_t* __restrict__ pair_bf,
                                                    float* __restrict__ mu,
                                                    float* __restrict__ rstd) {
  int row = blockIdx.x * 8 + (threadIdx.x >> 5);
  int l = threadIdx.x & 31;
  const float* src = pair + (size_t)row * kCZ + l * 4;
  float4_a x = *(const float4_a*)src;
  float s1 = x.x + x.y + x.z + x.w;
  float s2 = x.x * x.x + x.y * x.y + x.z * x.z + x.w * x.w;
#pragma unroll
  for (int off = 16; off > 0; off >>= 1) {
    s1 += __shfl_xor(s1, off);
    s2 += __shfl_xor(s2, off);
  }
  float m = s1 * (1.0f / kCZ);
  float v = s2 * (1.0f / kCZ) - m * m;
  float rs = rsqrtf(fmaxf(v, 0.0f) + EPSF);
  if (l == 0) {
    mu[row] = m;
    rstd[row] = rs;
  }
  uint2 u;
  u.x = (unsigned)f2bf(x.x) | ((unsigned)f2bf(x.y) << 16);
  u.y = (unsigned)f2bf(x.z) | ((unsigned)f2bf(x.w) << 16);
  *(uint2_a*)(pair_bf + (size_t)row * kCZ + l * 4) = u;
}

// ---------------- msa LN (fp32/bf16 src -> bf16 dst), vectorized ----------------
__global__ __launch_bounds__(256) void k_msa_ln(const float* __restrict__ src_f,
                                                const bf16_t* __restrict__ src_b,
                                                bf16_t* __restrict__ dst,
                                                const float* __restrict__ wall,
                                                const float* __restrict__ ball,
                                                int head, int first) {
  int row = blockIdx.x * 8 + (threadIdx.x >> 5);
  int l = threadIdx.x & 31;
  int c0 = l * 8;
  float x[8];
  if (first) {
    float4_a a = *(const float4_a*)(src_f + (size_t)row * kCM + c0);
    float4_a b = *(const float4_a*)(src_f + (size_t)row * kCM + c0 + 4);
    x[0] = a.x; x[1] = a.y; x[2] = a.z; x[3] = a.w;
    x[4] = b.x; x[5] = b.y; x[6] = b.z; x[7] = b.w;
  } else {
    union { bf16x8 v; bf16_t h[8]; } uu;
    uu.v = *(const bf16x8_a*)(src_b + (size_t)row * kCM + c0);
#pragma unroll
    for (int j = 0; j < 8; ++j) x[j] = bf2f(uu.h[j]);
  }
  float s1 = 0.f, s2 = 0.f;
#pragma unroll
  for (int j = 0; j < 8; ++j) {
    s1 += x[j];
    s2 += x[j] * x[j];
  }
#pragma unroll
  for (int off = 16; off > 0; off >>= 1) {
    s1 += __shfl_xor(s1, off);
    s2 += __shfl_xor(s2, off);
  }
  float m = s1 * (1.0f / kCM);
  float var = s2 * (1.0f / kCM) - m * m;
  float rs = rsqrtf(fmaxf(var, 0.0f) + EPSF);
  float4_a wa = *(const float4_a*)(wall + head * kCM + c0);
  float4_a wb4 = *(const float4_a*)(wall + head * kCM + c0 + 4);
  float4_a ba = *(const float4_a*)(ball + head * kCM + c0);
  float4_a bb4 = *(const float4_a*)(ball + head * kCM + c0 + 4);
  float wv[8] = {wa.x, wa.y, wa.z, wa.w, wb4.x, wb4.y, wb4.z, wb4.w};
  float bv[8] = {ba.x, ba.y, ba.z, ba.w, bb4.x, bb4.y, bb4.z, bb4.w};
  bf16_t h[8];
#pragma unroll
  for (int j = 0; j < 8; ++j) h[j] = f2bf((x[j] - m) * rs * wv[j] + bv[j]);
  uint4 u;
  u.x = (unsigned)h[0] | ((unsigned)h[1] << 16);
  u.y = (unsigned)h[2] | ((unsigned)h[3] << 16);
  u.z = (unsigned)h[4] | ((unsigned)h[5] << 16);
  u.w = (unsigned)h[6] | ((unsigned)h[7] << 16);
  *(uint4_a*)(dst + (size_t)row * kCM + c0) = u;
}

// ---------------- pack qkvg weights for ALL heads -> bf16 (H x 128 x 256) ----------------
__global__ __launch_bounds__(256) void k_pack_wcat_all(const float* __restrict__ wq,
                                                       const float* __restrict__ wk,
                                                       const float* __restrict__ wv,
                                                       const float* __restrict__ wg,
                                                       bf16_t* __restrict__ Wcat) {
  int gid = blockIdx.x * 256 + threadIdx.x;  // 0..262143
  int head = gid >> 15;
  int idx = gid & 32767;
  int j = idx >> 8;
  int c = idx & 255;
  const float* src = (j < 32) ? wq : (j < 64) ? wk : (j < 96) ? wv : wg;
  int d = j & 31;
  Wcat[gid] = f2bf(src[(head * kC + d) * kCM + c]);
}

// ---------------- pack bias weights (pair-LN + 1/sqrt(c) folded) for ALL heads ----------------
__global__ __launch_bounds__(256) void k_pack_bias_all(const float* __restrict__ wb,
                                                       const float* __restrict__ npw,
                                                       const float* __restrict__ npb,
                                                       bf16_t* __restrict__ wbeff,
                                                       float* __restrict__ beta,
                                                       float* __restrict__ sw) {
  int head = blockIdx.x;
  int j = threadIdx.x;  // 256 threads
  float sb = 0.f, ssw = 0.f;
  for (int c = 0; c < kCZ; ++c) {
    float w = wb[(head * kS + j) * kCZ + c];
    float e = w * npw[head * kCZ + c] * SCALEF;   // fold softmax scale
    wbeff[(size_t)head * kS * kCZ + j * kCZ + c] = f2bf(e);
    ssw += e;
    sb += w * npb[head * kCZ + c];
  }
  sw[head * kS + j] = ssw;
  beta[head * kS + j] = sb * SCALEF;
}

// ---------------- pack out_w -> bf16 ----------------
__global__ __launch_bounds__(256) void k_pack_outw(const float* __restrict__ in,
                                                   bf16_t* __restrict__ out) {
  int i = blockIdx.x * 256 + threadIdx.x;  // 65536
  out[i] = f2bf(in[i]);
}

// ---------------- qkvg GEMM MFMA: (kM x 256) x (128 x 256)^T ----------------
// q pre-scaled by 1/sqrt(c); g written into g_all[kM][256] at head slice.
__global__ __launch_bounds__(256) void k_gemm_qkvg_mx(const bf16_t* __restrict__ A,
                                                      const bf16_t* __restrict__ B,
                                                      bf16_t* __restrict__ q,
                                                      bf16_t* __restrict__ k,
                                                      bf16_t* __restrict__ v,
                                                      bf16_t* __restrict__ g_all,
                                                      int head) {
  __shared__ bf16_t As[128 * 32];
  __shared__ bf16_t Bs[128 * 32];
  int m0 = blockIdx.x * 128;
  int tid = threadIdx.x;
  int w = tid >> 6, L = tid & 63, l15 = L & 15, q4 = L >> 4;
  int wm = w >> 1, wn = w & 1;
  f32x4 acc[4][4] = {};
  for (int k0 = 0; k0 < 256; k0 += 32) {
#pragma unroll
    for (int rep = 0; rep < 2; ++rep) {
      int idx = tid + rep * 256;
      int row = idx >> 2, sg = idx & 3;
      *(uint4_a*)&As[row * 32 + sg * 8] = *(const uint4_a*)(A + (size_t)(m0 + row) * 256 + k0 + sg * 8);
      *(uint4_a*)&Bs[row * 32 + sg * 8] = *(const uint4_a*)(B + (size_t)row * 256 + k0 + sg * 8);
    }
    __syncthreads();
    bf16x8 af[4], bfr[4];
#pragma unroll
    for (int mt = 0; mt < 4; ++mt) af[mt] = *(const bf16x8_a*)&As[(wm * 64 + mt * 16 + l15) * 32 + q4 * 8];
#pragma unroll
    for (int nt = 0; nt < 4; ++nt) bfr[nt] = *(const bf16x8_a*)&Bs[(wn * 64 + nt * 16 + l15) * 32 + q4 * 8];
#pragma unroll
    for (int mt = 0; mt < 4; ++mt)
#pragma unroll
      for (int nt = 0; nt < 4; ++nt) acc[mt][nt] = MFMA16(af[mt], bfr[nt], acc[mt][nt]);
    __syncthreads();
  }
#pragma unroll
  for (int mt = 0; mt < 4; ++mt)
#pragma unroll
    for (int nt = 0; nt < 4; ++nt) {
      int n = wn * 64 + nt * 16 + l15;
      int mat = n >> 5, d = n & 31;
#pragma unroll
      for (int i = 0; i < 4; ++i) {
        int m = m0 + wm * 64 + mt * 16 + q4 * 4 + i;
        float val = acc[mt][nt][i];
        if (mat == 0) {
          q[(size_t)m * kC + d] = f2bf(val * SCALEF);
        } else if (mat == 1) {
          k[(size_t)m * kC + d] = f2bf(val);
        } else if (mat == 2) {
          v[(size_t)m * kC + d] = f2bf(val);
        } else {
          float sg = 1.0f / (1.0f + __expf(-val));
          g_all[(size_t)m * kCM + head * kC + d] = f2bf(sg);
        }
      }
    }
}

// ---------------- fused: bias-GEMM (from pair_bf) + QK^T + softmax(r) + PV + gate + hi/lo ------
// grid (kS): one block per s, 256 threads / 4 waves. Two internal t-half passes; PV partial
// accumulates in registers across both passes -> full t-sum -> g-gate + hi/lo bf16 output.
// Bias tile for block s = pair rows [s*576, s*576+576) @ wbeff^T, computed in 12 chunks of
// 48 m-rows (= 32 r-rows x all t) through LDS. Never touches HBM.
__global__ __launch_bounds__(256, 1) void k_attn_fused(const bf16_t* __restrict__ q,
                                                       const bf16_t* __restrict__ kmat,
                                                       const bf16_t* __restrict__ v,
                                                       const bf16_t* __restrict__ pair_bf,
                                                       const bf16_t* __restrict__ wbeff,
                                                       const float* __restrict__ mu,
                                                       const float* __restrict__ rstd,
                                                       const float* __restrict__ sw,
                                                       const float* __restrict__ beta,
                                                       const bf16_t* __restrict__ g_all,
                                                       bf16_t* __restrict__ ohi,
                                                       bf16_t* __restrict__ olo,
                                                       int head) {
  int s = blockIdx.x;
  int tid = threadIdx.x;
  int w = tid >> 6, L = tid & 63, l15 = L & 15, q4 = L >> 4;
  __shared__ bf16_t Wb[256 * 128];    // wbeff, k-XOR-swizzled           65536 B
  __shared__ bf16_t Ap[48 * 128];     // pair chunk, k-XOR-swizzled      12288 B
  __shared__ bf16_t BiasL[12288];     // bias chunk (flat, BSWZ)         24576 B
  __shared__ bf16_t vT[32 * 200];     // V^T half, padded                12800 B
  __shared__ bf16_t Psh[64 * 192];    // probs chunk, XOR-swizzled       24576 B

  int xw = (l15 & 7) << 3;  // k-group XOR for Ap/Wb reads (row&7 == l15&7)

  // ---- stage wbeff once (16B copies, swizzled) ----
#pragma unroll
  for (int rep = 0; rep < 16; ++rep) {
    int idx = tid + rep * 256;       // 4096
    int row = idx >> 4, kg = idx & 15;
    *(uint4_a*)&Wb[row * 128 + ((kg * 8) ^ ((row & 7) << 3))] =
        *(const uint4_a*)(wbeff + (size_t)row * 128 + kg * 8);
  }
  // per-thread n-column constants (n = w*64 + nt*16 + l15)
  float swv[4], betav[4];
#pragma unroll
  for (int nt = 0; nt < 4; ++nt) {
    int n = w * 64 + nt * 16 + l15;
    swv[nt] = sw[n];
    betav[nt] = beta[n];
  }
  __syncthreads();

  const bf16_t* qs = q + (size_t)s * kR * kC;
  const bf16_t* kp = kmat + (size_t)s * kR * kC;
  int prow = tid >> 4, pkg = tid & 15;  // pair-stage mapping (48 rows x 16 groups, 3 reps)
  const bf16_t* pbase = pair_bf + ((size_t)s * 576) * 128;

  f32x4 opacc[6][2] = {};

  for (int tb = 0; tb < 2; ++tb) {
    int tbase = tb * 192;
    int t0 = tbase + 48 * w;
    f32x4 acc[24][3];

    // ---- bias phase: 12 chunks of 48 m-rows, reg-prefetched staging ----
    uint4 pf0, pf1, pf2;
    pf0 = *(const uint4_a*)(pbase + (size_t)(prow)*128 + pkg * 8);
    pf1 = *(const uint4_a*)(pbase + (size_t)(16 + prow) * 128 + pkg * 8);
    pf2 = *(const uint4_a*)(pbase + (size_t)(32 + prow) * 128 + pkg * 8);
#pragma unroll
    for (int rc = 0; rc < 12; ++rc) {
      // write staged pair rows (swizzled), issue next chunk's loads
      *(uint4_a*)&Ap[prow * 128 + ((pkg * 8) ^ ((prow & 7) << 3))] = pf0;
      *(uint4_a*)&Ap[(16 + prow) * 128 + ((pkg * 8) ^ ((prow & 7) << 3))] = pf1;
      *(uint4_a*)&Ap[(32 + prow) * 128 + ((pkg * 8) ^ ((prow & 7) << 3))] = pf2;
      if (rc < 11) {
        const bf16_t* nb = pbase + (size_t)(rc + 1) * 48 * 128;
        pf0 = *(const uint4_a*)(nb + (size_t)(prow)*128 + pkg * 8);
        pf1 = *(const uint4_a*)(nb + (size_t)(16 + prow) * 128 + pkg * 8);
        pf2 = *(const uint4_a*)(nb + (size_t)(32 + prow) * 128 + pkg * 8);
      }
      __syncthreads();
      // 48x256 = A(48x128) @ B(256x128)^T ; wave w owns n in [w*64, w*64+64)
      f32x4 acc2[3][4] = {};
#pragma unroll
      for (int k0 = 0; k0 < 128; k0 += 32) {
        bf16x8 af[3], bfr[4];
#pragma unroll
        for (int mt = 0; mt < 3; ++mt)
          af[mt] = *(const bf16x8_a*)&Ap[(mt * 16 + l15) * 128 + ((k0 + q4 * 8) ^ xw)];
#pragma unroll
        for (int nt = 0; nt < 4; ++nt) {
          int n = w * 64 + nt * 16 + l15;
          bfr[nt] = *(const bf16x8_a*)&Wb[n * 128 + ((k0 + q4 * 8) ^ xw)];
        }
#pragma unroll
        for (int mt = 0; mt < 3; ++mt)
#pragma unroll
          for (int nt = 0; nt < 4; ++nt) acc2[mt][nt] = MFMA16(af[mt], bfr[nt], acc2[mt][nt]);
      }
      // epilogue: LN-stats fold -> BiasL (flat bf16)
      int pg = s * 576 + rc * 48;
#pragma unroll
      for (int mt = 0; mt < 3; ++mt)
#pragma unroll
        for (int i = 0; i < 4; ++i) {
          int m_loc = mt * 16 + q4 * 4 + i;
          float mp = mu[pg + m_loc], rp = rstd[pg + m_loc];
#pragma unroll
          for (int nt = 0; nt < 4; ++nt) {
            int n = w * 64 + nt * 16 + l15;
            int fl = m_loc * 256 + n;
            BiasL[BSWZ(fl)] = f2bf(rp * (acc2[mt][nt][i] - mp * swv[nt]) + betav[nt]);
          }
        }
      __syncthreads();
      // init acc rows of this 32-r chunk from bias
#pragma unroll
      for (int rt2 = 0; rt2 < 2; ++rt2)
#pragma unroll
        for (int tt = 0; tt < 3; ++tt)
#pragma unroll
          for (int i = 0; i < 4; ++i) {
            int r_loc = rt2 * 16 + q4 * 4 + i;
            int t = t0 + tt * 16 + l15;
            int fl = r_loc * 384 + t;
            acc[rc * 2 + rt2][tt][i] = bf2f(BiasL[BSWZ(fl)]);
          }
    }

    // ---- QK^T (q pre-scaled by 1/sqrt(c)) ----
    bf16x8 bk[3];
#pragma unroll
    for (int tt = 0; tt < 3; ++tt)
      bk[tt] = *(const bf16x8_a*)(kp + (size_t)(t0 + tt * 16 + l15) * kC + q4 * 8);
#pragma unroll
    for (int rt = 0; rt < 24; ++rt) {
      bf16x8 af = *(const bf16x8_a*)(qs + (size_t)(rt * 16 + l15) * kC + q4 * 8);
#pragma unroll
      for (int tt = 0; tt < 3; ++tt) acc[rt][tt] = MFMA16(af, bk[tt], acc[rt][tt]);
    }

    // ---- softmax over r (wave-local) ----
    float mx[3] = {-3.0e38f, -3.0e38f, -3.0e38f};
#pragma unroll
    for (int rt = 0; rt < 24; ++rt)
#pragma unroll
      for (int tt = 0; tt < 3; ++tt)
#pragma unroll
        for (int i = 0; i < 4; ++i) mx[tt] = fmaxf(mx[tt], acc[rt][tt][i]);
#pragma unroll
    for (int tt = 0; tt < 3; ++tt) {
      mx[tt] = fmaxf(mx[tt], __shfl_xor(mx[tt], 16));
      mx[tt] = fmaxf(mx[tt], __shfl_xor(mx[tt], 32));
    }
    float sm[3] = {0.f, 0.f, 0.f};
#pragma unroll
    for (int rt = 0; rt < 24; ++rt)
#pragma unroll
      for (int tt = 0; tt < 3; ++tt)
#pragma unroll
        for (int i = 0; i < 4; ++i) {
          float e = __expf(acc[rt][tt][i] - mx[tt]);
          acc[rt][tt][i] = e;
          sm[tt] += e;
        }
#pragma unroll
    for (int tt = 0; tt < 3; ++tt) {
      sm[tt] += __shfl_xor(sm[tt], 16);
      sm[tt] += __shfl_xor(sm[tt], 32);
    }
    float di[3];
#pragma unroll
    for (int tt = 0; tt < 3; ++tt) di[tt] = 1.0f / sm[tt];

    // ---- stage V^T for this t-half ----
#pragma unroll
    for (int rep = 0; rep < 3; ++rep) {
      int idx = tid + rep * 256;  // 768 = 192 t * 4 sg
      int t = idx >> 2, sg = idx & 3;
      union { uint4 u; bf16_t h[8]; } uu;
      uu.u = *(const uint4_a*)(v + (size_t)(s * kR + tbase + t) * kC + sg * 8);
#pragma unroll
      for (int j = 0; j < 8; ++j) vT[(sg * 8 + j) * 200 + t] = uu.h[j];
    }
    __syncthreads();
    bf16x8 bfv[12];
#pragma unroll
    for (int kk = 0; kk < 6; ++kk)
#pragma unroll
      for (int ct = 0; ct < 2; ++ct)
        bfv[kk * 2 + ct] = *(const bf16x8_a*)&vT[(ct * 16 + l15) * 200 + kk * 32 + q4 * 8];

    // ---- PV in 6 chunks of 64 r-rows; accumulate across t-halves ----
#pragma unroll
    for (int c = 0; c < 6; ++c) {
#pragma unroll
      for (int j = 0; j < 4; ++j)
#pragma unroll
        for (int tt = 0; tt < 3; ++tt)
#pragma unroll
          for (int i = 0; i < 4; ++i) {
            int rl = j * 16 + q4 * 4 + i;
            int tl = 48 * w + tt * 16 + l15;
            Psh[rl * 192 + (tl ^ ((rl & 7) << 3))] = f2bf(acc[4 * c + j][tt][i] * di[tt]);
          }
      __syncthreads();
      int rr = w * 16 + l15;
#pragma unroll
      for (int kk = 0; kk < 6; ++kk) {
        int e = kk * 32 + q4 * 8;
        bf16x8 af = *(const bf16x8_a*)&Psh[rr * 192 + (e ^ ((rr & 7) << 3))];
#pragma unroll
        for (int ct = 0; ct < 2; ++ct) opacc[c][ct] = MFMA16(af, bfv[kk * 2 + ct], opacc[c][ct]);
      }
      __syncthreads();
    }
  }

  // ---- epilogue: gate with g, hi/lo bf16 split, store ----
  const bf16_t* gp = g_all + (size_t)s * kR * kCM + head * kC;
#pragma unroll
  for (int c = 0; c < 6; ++c)
#pragma unroll
    for (int ct = 0; ct < 2; ++ct)
#pragma unroll
      for (int i = 0; i < 4; ++i) {
        int r = c * 64 + w * 16 + q4 * 4 + i;
        int cc = ct * 16 + l15;
        float val = opacc[c][ct][i] * bf2f(gp[(size_t)r * kCM + cc]);
        bf16_t hi = f2bf(val);
        bf16_t lo = f2bf(val - bf2f(hi));
        size_t oidx = (size_t)(s * kR + r) * kCM + head * kC + cc;
        ohi[oidx] = hi;
        olo[oidx] = lo;
      }
}

// ---------------- final GEMM: (Ahi,Alo bf16 kM x 256) x (256 x 256)^T bf16 -> out ----------------
__global__ __launch_bounds__(256) void k_gemm_final_mx(const bf16_t* __restrict__ Ahi,
                                                       const bf16_t* __restrict__ Alo,
                                                       const bf16_t* __restrict__ Bw,
                                                       const float* __restrict__ bias,
                                                       float* __restrict__ out) {
  __shared__ bf16_t As[2 * 64 * 32];  // [half][row][k]
  __shared__ bf16_t Bs[256 * 32];
  int m0 = blockIdx.x * 64;
  int tid = threadIdx.x;
  int w = tid >> 6, L = tid & 63, l15 = L & 15, q4 = L >> 4;
  f32x4 acc[4][4] = {};  // [mt][nt]
  for (int kc = 0; kc < 256; kc += 32) {
    {
      int row = tid >> 2, sg = tid & 3;
      size_t base = (size_t)(m0 + row) * kCM + kc + sg * 8;
      *(uint4_a*)&As[row * 32 + sg * 8] = *(const uint4_a*)(Ahi + base);
      *(uint4_a*)&As[2048 + row * 32 + sg * 8] = *(const uint4_a*)(Alo + base);
    }
#pragma unroll
    for (int rep = 0; rep < 4; ++rep) {
      int idx = tid + rep * 256;
      int row = idx >> 2, sg = idx & 3;
      *(uint4_a*)&Bs[row * 32 + sg * 8] = *(const uint4_a*)(Bw + (size_t)row * kCM + kc + sg * 8);
    }
    __syncthreads();
    bf16x8 bfr[4];
#pragma unroll
    for (int nt = 0; nt < 4; ++nt) bfr[nt] = *(const bf16x8_a*)&Bs[(w * 64 + nt * 16 + l15) * 32 + q4 * 8];
#pragma unroll
    for (int half = 0; half < 2; ++half)
#pragma unroll
      for (int mt = 0; mt < 4; ++mt) {
        bf16x8 af = *(const bf16x8_a*)&As[half * 2048 + (mt * 16 + l15) * 32 + q4 * 8];
#pragma unroll
        for (int nt = 0; nt < 4; ++nt) acc[mt][nt] = MFMA16(af, bfr[nt], acc[mt][nt]);
      }
    __syncthreads();
  }
#pragma unroll
  for (int mt = 0; mt < 4; ++mt)
#pragma unroll
    for (int nt = 0; nt < 4; ++nt) {
      int n = w * 64 + nt * 16 + l15;
      float bn = bias[n];
#pragma unroll
      for (int i = 0; i < 4; ++i) {
        int m = m0 + mt * 16 + q4 * 4 + i;
        out[(size_t)m * kCM + n] = acc[mt][nt][i] + bn;
      }
    }
}

extern "C" void kernel_launch(void* const* d_in, const int* in_sizes, int n_in,
                              void* d_out, int out_size, void* d_ws, size_t ws_size,
                              hipStream_t stream) {
  (void)in_sizes; (void)n_in; (void)out_size; (void)ws_size;
  const float* msa_in = (const float*)d_in[0];
  const float* pair   = (const float*)d_in[1];
  const float* nmw    = (const float*)d_in[2];
  const float* nmb    = (const float*)d_in[3];
  const float* wq     = (const float*)d_in[4];
  const float* wk     = (const float*)d_in[5];
  const float* wv     = (const float*)d_in[6];
  const float* npw    = (const float*)d_in[7];
  const float* npb    = (const float*)d_in[8];
  const float* wb     = (const float*)d_in[9];
  const float* wg     = (const float*)d_in[10];
  const float* outw   = (const float*)d_in[11];
  const float* outb   = (const float*)d_in[12];
  float* out = (float*)d_out;

  char* ws = (char*)d_ws;
  size_t off = 0;
  bf16_t* msa_cur  = (bf16_t*)(ws + off); off += (size_t)kM * kCM * 2;    // 50,331,648
  bf16_t* pair_bf  = (bf16_t*)(ws + off); off += (size_t)kP * kCZ * 2;    // 37,748,736
  bf16_t* qb       = (bf16_t*)(ws + off); off += (size_t)kM * kC * 2;     // 6,291,456
  bf16_t* kb       = (bf16_t*)(ws + off); off += (size_t)kM * kC * 2;
  bf16_t* vb       = (bf16_t*)(ws + off); off += (size_t)kM * kC * 2;
  bf16_t* g_all    = (bf16_t*)(ws + off); off += (size_t)kM * kCM * 2;    // 50,331,648
  bf16_t* ohi      = (bf16_t*)(ws + off); off += (size_t)kM * kCM * 2;    // 50,331,648
  bf16_t* olo      = (bf16_t*)(ws + off); off += (size_t)kM * kCM * 2;    // 50,331,648
  float* mu_p      = (float*)(ws + off);  off += (size_t)kP * 4;          // 589,824
  float* rstd_p    = (float*)(ws + off);  off += (size_t)kP * 4;
  bf16_t* Wcat_all = (bf16_t*)(ws + off); off += (size_t)kH * 128 * 256 * 2;
  bf16_t* wbef_all = (bf16_t*)(ws + off); off += (size_t)kH * 256 * 128 * 2;
  bf16_t* outw_bf  = (bf16_t*)(ws + off); off += (size_t)256 * 256 * 2;
  float* beta_all  = (float*)(ws + off);  off += (size_t)kH * 256 * 4;
  float* sw_all    = (float*)(ws + off);  off += (size_t)kH * 256 * 4;
  // total ~266 MB

  // setup (off the per-head critical path)
  k_pair_fused<<<kP / 8, 256, 0, stream>>>(pair, pair_bf, mu_p, rstd_p);
  k_pack_outw<<<256, 256, 0, stream>>>(outw, outw_bf);
  k_pack_wcat_all<<<kH * 128, 256, 0, stream>>>(wq, wk, wv, wg, Wcat_all);
  k_pack_bias_all<<<kH, 256, 0, stream>>>(wb, npw, npb, wbef_all, beta_all, sw_all);

  for (int h = 0; h < kH; ++h) {
    k_msa_ln<<<kM / 8, 256, 0, stream>>>(msa_in, msa_cur, msa_cur, nmw, nmb, h, h == 0 ? 1 : 0);
    k_gemm_qkvg_mx<<<kM / 128, 256, 0, stream>>>(msa_cur, Wcat_all + (size_t)h * 128 * 256,
                                                 qb, kb, vb, g_all, h);
    k_attn_fused<<<kS, 256, 0, stream>>>(qb, kb, vb, pair_bf,
                                         wbef_all + (size_t)h * 256 * 128,
                                         mu_p, rstd_p,
                                         sw_all + h * 256, beta_all + h * 256,
                                         g_all, ohi, olo, h);
  }

  k_gemm_final_mx<<<kM / 64, 256, 0, stream>>>(ohi, olo, outw_bf, outb, out);
}